// Round 5
// baseline (252.044 us; speedup 1.0000x reference)
//
#include <hip/hip_runtime.h>
#include <math.h>

// Problem constants (reference: n=8192, d=4096, fp32)
#define NROWS 8192
#define NCOLS 4096
#define NCOLS4 (NCOLS / 4)
#define TEMP_INV 0.01f              // 1/TEMPERATURE

#define STRIPS 4                    // column strips of 1024 floats
#define CHUNKS 256                  // row chunks
#define CHUNK_ROWS (NROWS / CHUNKS) // 32
#define STREAM_BLKS (STRIPS * CHUNKS) // 1024 blocks, 4 per CU

// ---- Kernel 1: per-chunk partial column sums (pure stores) -----------------
__global__ __launch_bounds__(256)
void colsum_partial_kernel(const float* __restrict__ g,
                           float* __restrict__ partial) {
    const int strip = blockIdx.x & (STRIPS - 1);
    const int chunk = blockIdx.x >> 2;
    const int col   = strip * 1024 + threadIdx.x * 4;
    const float* p  = g + (size_t)chunk * CHUNK_ROWS * NCOLS + col;
    float4 acc = make_float4(0.f, 0.f, 0.f, 0.f);
    #pragma unroll
    for (int r = 0; r < CHUNK_ROWS; ++r) {
        float4 v = *reinterpret_cast<const float4*>(p);
        acc.x += v.x; acc.y += v.y; acc.z += v.z; acc.w += v.w;
        p += NCOLS;
    }
    *reinterpret_cast<float4*>(partial + (size_t)chunk * NCOLS + col) = acc;
}

// ---- Kernel 2: reduce partial[CHUNKS][NCOLS] -> colsum[NCOLS] --------------
// 64 blocks x 256 threads; 16 f4-cols per block, 16 chunk-groups
__global__ __launch_bounds__(256)
void reduce_kernel(const float* __restrict__ partial, float* __restrict__ dst) {
    const int tid = threadIdx.x;
    const int f4  = blockIdx.x * 16 + (tid & 15);
    const int grp = tid >> 4;
    const float4* p4 = reinterpret_cast<const float4*>(partial);
    float4 acc = make_float4(0.f, 0.f, 0.f, 0.f);
    #pragma unroll 4
    for (int c = grp; c < CHUNKS; c += 16) {
        float4 v = p4[(size_t)c * NCOLS4 + f4];
        acc.x += v.x; acc.y += v.y; acc.z += v.z; acc.w += v.w;
    }
    __shared__ float4 red[256];
    red[tid] = acc;
    __syncthreads();
    #pragma unroll
    for (int s = 128; s >= 16; s >>= 1) {
        if (tid < s) {
            float4 o = red[tid + s];
            red[tid].x += o.x; red[tid].y += o.y;
            red[tid].z += o.z; red[tid].w += o.w;
        }
        __syncthreads();
    }
    if (tid < 16)
        reinterpret_cast<float4*>(dst)[blockIdx.x * 16 + tid] = red[tid];
}

// ---- Kernel 3: scores[i] = G[i,:] . colsum ; blocks 0-3 zero d_out ---------
// 2048 blocks x 256 threads; 1 row per wave
__global__ __launch_bounds__(256)
void scores_kernel(const float* __restrict__ g, const float* __restrict__ colsum,
                   float* __restrict__ scores, float* __restrict__ out) {
    __shared__ float4 cs4[NCOLS4];
    #pragma unroll
    for (int k = 0; k < NCOLS4 / 256; ++k)
        cs4[k * 256 + threadIdx.x] =
            reinterpret_cast<const float4*>(colsum)[k * 256 + threadIdx.x];
    if (blockIdx.x < 4)   // zero output accumulator (pool runs after us)
        reinterpret_cast<float4*>(out)[blockIdx.x * 256 + threadIdx.x] =
            make_float4(0.f, 0.f, 0.f, 0.f);
    __syncthreads();

    const int wave = threadIdx.x >> 6;
    const int lane = threadIdx.x & 63;
    const int row  = blockIdx.x * 4 + wave;
    const float4* gp = reinterpret_cast<const float4*>(g) + (size_t)row * NCOLS4;

    float4 acc = make_float4(0.f, 0.f, 0.f, 0.f);   // 4 independent FMA chains
    #pragma unroll
    for (int k = 0; k < 16; ++k) {
        const int idx = k * 64 + lane;
        float4 v = gp[idx];
        float4 c = cs4[idx];
        acc.x += v.x * c.x; acc.y += v.y * c.y;
        acc.z += v.z * c.z; acc.w += v.w * c.w;
    }
    float s = (acc.x + acc.y) + (acc.z + acc.w);
    #pragma unroll
    for (int off = 32; off; off >>= 1) s += __shfl_xor(s, off, 64);
    if (lane == 0) scores[row] = s;
}

// ---- Kernel 4: per-block redundant softmax stats + weighted pooling --------
// 1024 blocks x 256 threads; atomicAdd into pre-zeroed d_out
__global__ __launch_bounds__(256)
void pool_kernel(const float* __restrict__ g, const float* __restrict__ scores,
                 float* __restrict__ out) {
    const int tid   = threadIdx.x;
    const int strip = blockIdx.x & (STRIPS - 1);
    const int chunk = blockIdx.x >> 2;
    const int wave  = tid >> 6;
    const int lane  = tid & 63;

    __shared__ float red[8];
    __shared__ float wsm[CHUNK_ROWS];

    // stage all 8192 scores into registers (32 per thread)
    const float4* s4 = reinterpret_cast<const float4*>(scores);
    float4 sv[8];
    float lm = -INFINITY;
    #pragma unroll
    for (int k = 0; k < 8; ++k) {
        sv[k] = s4[k * 256 + tid];
        lm = fmaxf(lm, fmaxf(fmaxf(sv[k].x, sv[k].y), fmaxf(sv[k].z, sv[k].w)));
    }
    #pragma unroll
    for (int off = 32; off; off >>= 1) lm = fmaxf(lm, __shfl_xor(lm, off, 64));
    if (lane == 0) red[wave] = lm;
    __syncthreads();
    const float m = fmaxf(fmaxf(red[0], red[1]), fmaxf(red[2], red[3]));

    float ls = 0.f;
    #pragma unroll
    for (int k = 0; k < 8; ++k) {
        ls += __expf((sv[k].x - m) * TEMP_INV)
            + __expf((sv[k].y - m) * TEMP_INV)
            + __expf((sv[k].z - m) * TEMP_INV)
            + __expf((sv[k].w - m) * TEMP_INV);
    }
    #pragma unroll
    for (int off = 32; off; off >>= 1) ls += __shfl_xor(ls, off, 64);
    if (lane == 0) red[4 + wave] = ls;
    __syncthreads();
    const float invZ = 1.0f / (red[4] + red[5] + red[6] + red[7]);

    // weights for this block's rows
    if (tid < CHUNK_ROWS) {
        const float s = scores[chunk * CHUNK_ROWS + tid];
        wsm[tid] = __expf((s - m) * TEMP_INV) * invZ;
    }
    __syncthreads();

    const int col  = strip * 1024 + tid * 4;
    const float* p = g + (size_t)chunk * CHUNK_ROWS * NCOLS + col;
    float4 acc = make_float4(0.f, 0.f, 0.f, 0.f);
    #pragma unroll
    for (int r = 0; r < CHUNK_ROWS; ++r) {
        const float wt = wsm[r];            // LDS broadcast, conflict-free
        float4 v = *reinterpret_cast<const float4*>(p);
        acc.x += wt * v.x; acc.y += wt * v.y;
        acc.z += wt * v.z; acc.w += wt * v.w;
        p += NCOLS;
    }
    atomicAdd(&out[col + 0], acc.x);
    atomicAdd(&out[col + 1], acc.y);
    atomicAdd(&out[col + 2], acc.z);
    atomicAdd(&out[col + 3], acc.w);
}

extern "C" void kernel_launch(void* const* d_in, const int* in_sizes, int n_in,
                              void* d_out, int out_size, void* d_ws, size_t ws_size,
                              hipStream_t stream) {
    const float* grad = (const float*)d_in[0];
    float* out = (float*)d_out;

    // ws layout: partial [256][4096] f32 (4 MiB), colsum [4096], scores [8192]
    float* partial = (float*)d_ws;
    float* colsum  = partial + (size_t)CHUNKS * NCOLS;
    float* scores  = colsum + NCOLS;

    colsum_partial_kernel<<<STREAM_BLKS, 256, 0, stream>>>(grad, partial);
    reduce_kernel<<<64, 256, 0, stream>>>(partial, colsum);
    scores_kernel<<<NROWS / 4, 256, 0, stream>>>(grad, colsum, scores, out);
    pool_kernel<<<STREAM_BLKS, 256, 0, stream>>>(grad, scores, out);
}